// Round 7
// baseline (151.986 us; speedup 1.0000x reference)
//
#include <hip/hip_runtime.h>

#define IN_DIM 256
#define OUT_DIM 128
#define N_CLS 40

#define SLICE 8192     // nodes per LDS histogram slice (2 x 32 KB LDS)
#define NE_CH 20       // edge chunks

typedef __attribute__((ext_vector_type(8))) short short8;
typedef __attribute__((ext_vector_type(4))) float floatx4;

static __device__ __forceinline__ unsigned short f2bf(float f) {
    union { float f; unsigned u; } v; v.f = f;
    unsigned r = v.u + 0x7FFF + ((v.u >> 16) & 1);
    return (unsigned short)(r >> 16);
}

// ---------------------------------------------------------------------------
// Kernel 1: LDS-privatized histograms -> partial_out/partial_in [NE_CH][n],
// PLUS (merged) Wt[col][k] = bf16(W[k][col]) in trailing blocks.
// ---------------------------------------------------------------------------
__global__ __launch_bounds__(256) void hist_wconv_kernel(
    const int* __restrict__ src, const int* __restrict__ dst,
    int* __restrict__ partial_out, int* __restrict__ partial_in,
    const float* __restrict__ W, unsigned short* __restrict__ Wt,
    int ne, int n, int chunk, int nbh)
{
    __shared__ __align__(16) int lh_out[SLICE];
    __shared__ __align__(16) int lh_in[SLICE];

    const int tid = threadIdx.x;

    if (blockIdx.x >= nbh) {           // wconv part
        int t = (blockIdx.x - nbh) * 256 + tid;
        if (t < IN_DIM * OUT_DIM) {
            int k = t >> 7, c = t & 127;
            Wt[c * IN_DIM + k] = f2bf(W[t]);
        }
        return;
    }

    const int s = blockIdx.x / NE_CH;
    const int e = blockIdx.x % NE_CH;
    const int lo = s * SLICE;
    const int hi = min(lo + SLICE, n);

    for (int i = tid; i < SLICE; i += 256) { lh_out[i] = 0; lh_in[i] = 0; }
    __syncthreads();

    const int start = e * chunk;
    const int end = min(start + chunk, ne);
    const int cnt4 = (end - start) >> 2;
    const int4* s4 = (const int4*)(src + start);
    const int4* d4 = (const int4*)(dst + start);
    for (int k = tid; k < cnt4; k += 256) {
        int4 sv = s4[k];
        int4 dv = d4[k];
        unsigned q;
        q = (unsigned)(sv.x - lo); if (q < SLICE) atomicAdd(&lh_out[q], 1);
        q = (unsigned)(sv.y - lo); if (q < SLICE) atomicAdd(&lh_out[q], 1);
        q = (unsigned)(sv.z - lo); if (q < SLICE) atomicAdd(&lh_out[q], 1);
        q = (unsigned)(sv.w - lo); if (q < SLICE) atomicAdd(&lh_out[q], 1);
        q = (unsigned)(dv.x - lo); if (q < SLICE) atomicAdd(&lh_in[q], 1);
        q = (unsigned)(dv.y - lo); if (q < SLICE) atomicAdd(&lh_in[q], 1);
        q = (unsigned)(dv.z - lo); if (q < SLICE) atomicAdd(&lh_in[q], 1);
        q = (unsigned)(dv.w - lo); if (q < SLICE) atomicAdd(&lh_in[q], 1);
    }
    for (int t = start + (cnt4 << 2) + tid; t < end; t += 256) {
        unsigned q;
        q = (unsigned)(src[t] - lo); if (q < SLICE) atomicAdd(&lh_out[q], 1);
        q = (unsigned)(dst[t] - lo); if (q < SLICE) atomicAdd(&lh_in[q], 1);
    }
    __syncthreads();

    const int cnt = hi - lo;
    const int c4 = cnt >> 2;
    int4* po = (int4*)(partial_out + (size_t)e * n + lo);
    int4* pi = (int4*)(partial_in + (size_t)e * n + lo);
    for (int i = tid; i < c4; i += 256) {
        po[i] = ((const int4*)lh_out)[i];
        pi[i] = ((const int4*)lh_in)[i];
    }
    for (int i = (c4 << 2) + tid; i < cnt; i += 256) {
        partial_out[(size_t)e * n + lo + i] = lh_out[i];
        partial_in[(size_t)e * n + lo + i] = lh_in[i];
    }
}

// ---------------------------------------------------------------------------
// Kernel 2: reduce partials -> cnt_out, cnt_in; partial_in -> exclusive
// prefix along the chunk axis.
// ---------------------------------------------------------------------------
__global__ __launch_bounds__(256) void reduce_kernel(
    int* __restrict__ partial_out, int* __restrict__ partial_in,
    int* __restrict__ cnt_out, int* __restrict__ cnt_in, int n)
{
    const int g = blockIdx.x * 256 + threadIdx.x;
    const int ng4 = n >> 2;
    if (g < ng4) {
        const size_t base = (size_t)g * 4;
        int4 sum = make_int4(0, 0, 0, 0);
#pragma unroll
        for (int e = 0; e < NE_CH; e++) {
            int4 v = *(const int4*)(partial_out + (size_t)e * n + base);
            sum.x += v.x; sum.y += v.y; sum.z += v.z; sum.w += v.w;
        }
        *(int4*)(cnt_out + base) = sum;

        int4 run = make_int4(0, 0, 0, 0);
#pragma unroll
        for (int e = 0; e < NE_CH; e++) {
            int* p = partial_in + (size_t)e * n + base;
            int4 v = *(const int4*)p;
            *(int4*)p = run;
            run.x += v.x; run.y += v.y; run.z += v.z; run.w += v.w;
        }
        *(int4*)(cnt_in + base) = run;
    }
    const int t = (ng4 << 2) + g;
    if (t < n) {
        int sum = 0;
#pragma unroll
        for (int e = 0; e < NE_CH; e++) sum += partial_out[(size_t)e * n + t];
        cnt_out[t] = sum;
        int run = 0;
#pragma unroll
        for (int e = 0; e < NE_CH; e++) {
            int v = partial_in[(size_t)e * n + t];
            partial_in[(size_t)e * n + t] = run;
            run += v;
        }
        cnt_in[t] = run;
    }
}

// ---------------------------------------------------------------------------
// Kernel 3: single-block exclusive scan of cnt_in -> row_start[n+1]
// ---------------------------------------------------------------------------
__global__ __launch_bounds__(1024) void scan_kernel(
    const int* __restrict__ cnt, int* __restrict__ row_start, int n)
{
    __shared__ int wsum[16];
    __shared__ int carry_s;
    const int tid = threadIdx.x;
    const int lane = tid & 63, wid = tid >> 6;
    if (tid == 0) carry_s = 0;
    __syncthreads();

    for (int chunk = 0; chunk < n; chunk += 8192) {
        int base = chunk + tid * 8;
        int v[8];
        if (base + 8 <= n) {
            int4 a = *(const int4*)&cnt[base];
            int4 b = *(const int4*)&cnt[base + 4];
            v[0]=a.x; v[1]=a.y; v[2]=a.z; v[3]=a.w;
            v[4]=b.x; v[5]=b.y; v[6]=b.z; v[7]=b.w;
        } else {
#pragma unroll
            for (int t = 0; t < 8; t++) v[t] = (base + t < n) ? cnt[base + t] : 0;
        }
        int tsum = 0;
#pragma unroll
        for (int t = 0; t < 8; t++) tsum += v[t];

        int incl = tsum;
#pragma unroll
        for (int off = 1; off < 64; off <<= 1) {
            int q = __shfl_up(incl, (unsigned)off, 64);
            if (lane >= off) incl += q;
        }
        if (lane == 63) wsum[wid] = incl;
        __syncthreads();
        int woff = 0;
        for (int w = 0; w < wid; ++w) woff += wsum[w];
        int carry = carry_s;
        int run = carry + woff + (incl - tsum);
        if (base + 8 <= n) {
            int o[8];
#pragma unroll
            for (int t = 0; t < 8; t++) { o[t] = run; run += v[t]; }
            int4 r0, r1;
            r0.x=o[0]; r0.y=o[1]; r0.z=o[2]; r0.w=o[3];
            r1.x=o[4]; r1.y=o[5]; r1.z=o[6]; r1.w=o[7];
            *(int4*)&row_start[base]     = r0;
            *(int4*)&row_start[base + 4] = r1;
        } else {
#pragma unroll
            for (int t = 0; t < 8; t++) {
                if (base + t < n) row_start[base + t] = run;
                run += v[t];
            }
        }
        __syncthreads();
        if (tid == 1023) carry_s = carry + woff + incl;
        __syncthreads();
    }
    if (tid == 0) row_start[n] = carry_s;
}

// ---------------------------------------------------------------------------
// Kernel 4: scatter with LDS cursors (no global atomics).
// ---------------------------------------------------------------------------
__global__ __launch_bounds__(256) void scatter_lds_kernel(
    const int* __restrict__ src, const int* __restrict__ dst,
    const int* __restrict__ row_start, const int* __restrict__ prefix_in,
    int* __restrict__ csr_src, int ne, int n, int chunk)
{
    __shared__ __align__(16) int cur[SLICE];

    const int tid = threadIdx.x;
    const int s = blockIdx.x / NE_CH;
    const int e = blockIdx.x % NE_CH;
    const int lo = s * SLICE;
    const int hi = min(lo + SLICE, n);
    const int cnt = hi - lo;

    const int c4 = cnt >> 2;
    for (int i = tid; i < c4; i += 256) {
        int4 rs = *(const int4*)(row_start + lo + i * 4);
        int4 pf = *(const int4*)(prefix_in + (size_t)e * n + lo + i * 4);
        rs.x += pf.x; rs.y += pf.y; rs.z += pf.z; rs.w += pf.w;
        ((int4*)cur)[i] = rs;
    }
    for (int i = (c4 << 2) + tid; i < cnt; i += 256)
        cur[i] = row_start[lo + i] + prefix_in[(size_t)e * n + lo + i];
    __syncthreads();

    const int start = e * chunk;
    const int end = min(start + chunk, ne);
    const int cnt4e = (end - start) >> 2;
    const int4* s4 = (const int4*)(src + start);
    const int4* d4 = (const int4*)(dst + start);
    for (int k = tid; k < cnt4e; k += 256) {
        int4 sv = s4[k];
        int4 dv = d4[k];
        unsigned q;
        q = (unsigned)(dv.x - lo); if (q < SLICE) csr_src[atomicAdd(&cur[q], 1)] = sv.x;
        q = (unsigned)(dv.y - lo); if (q < SLICE) csr_src[atomicAdd(&cur[q], 1)] = sv.y;
        q = (unsigned)(dv.z - lo); if (q < SLICE) csr_src[atomicAdd(&cur[q], 1)] = sv.z;
        q = (unsigned)(dv.w - lo); if (q < SLICE) csr_src[atomicAdd(&cur[q], 1)] = sv.w;
    }
    for (int t = start + (cnt4e << 2) + tid; t < end; t += 256) {
        unsigned q = (unsigned)(dst[t] - lo);
        if (q < SLICE) csr_src[atomicAdd(&cur[q], 1)] = src[t];
    }
}

// ---------------------------------------------------------------------------
// Kernel 5: h = bf16( (emb[nodes]) @ W ) * rsqrt(deg) via bf16 MFMA.
// 128x128 tile, 4 waves (2x2), each wave 64x64 (4x4 16x16 frags), K-step 32.
// Row-scale applied in f32 epilogue.
// ---------------------------------------------------------------------------
__global__ __launch_bounds__(256) void gemm1_mfma_kernel(
    const int* __restrict__ nodes, const float* __restrict__ emb,
    const unsigned short* __restrict__ Wt, const int* __restrict__ cnt_out,
    unsigned short* __restrict__ h, int n)
{
    __shared__ unsigned short A_lds[128 * 40];
    __shared__ unsigned short B_lds[128 * 40];
    __shared__ int   snode[128];
    __shared__ float sscale[128];

    const int tid = threadIdx.x;
    const int m0  = blockIdx.x * 128;

    if (tid < 128) {
        int gr = m0 + tid;
        snode[tid]  = (gr < n) ? nodes[gr] : 0;
        sscale[tid] = (gr < n) ? rsqrtf(fmaxf((float)cnt_out[gr], 1.0f)) : 0.0f;
    }
    __syncthreads();

    // staging roles: A: 2 thr/row x 16 floats; B: 2 thr/col x 16 bf16
    const int arow = tid >> 1, aq = tid & 1;
    const float* aptr = emb + (size_t)snode[arow] * IN_DIM + aq * 16;
    const unsigned short* bptr = Wt + arow * IN_DIM + aq * 16;

    float    ar[16];
    unsigned bw[8];

#define LOAD_REGS(KK) do {                                           \
        _Pragma("unroll")                                            \
        for (int q = 0; q < 4; q++) {                                \
            const floatx4 v = *(const floatx4*)(aptr + (KK) * 32 + q * 4); \
            ar[q*4+0]=v[0]; ar[q*4+1]=v[1]; ar[q*4+2]=v[2]; ar[q*4+3]=v[3]; \
        }                                                            \
        const uint4 w0 = *(const uint4*)(bptr + (KK) * 32);          \
        const uint4 w1 = *(const uint4*)(bptr + (KK) * 32 + 8);      \
        bw[0]=w0.x; bw[1]=w0.y; bw[2]=w0.z; bw[3]=w0.w;              \
        bw[4]=w1.x; bw[5]=w1.y; bw[6]=w1.z; bw[7]=w1.w;              \
    } while (0)

#define WRITE_LDS() do {                                             \
        union { unsigned short s[16]; uint4 v[2]; } ua;              \
        _Pragma("unroll")                                            \
        for (int i = 0; i < 16; i++) ua.s[i] = f2bf(ar[i]);          \
        *(uint4*)&A_lds[arow * 40 + aq * 16]     = ua.v[0];          \
        *(uint4*)&A_lds[arow * 40 + aq * 16 + 8] = ua.v[1];          \
        uint4 b0, b1;                                                \
        b0.x=bw[0]; b0.y=bw[1]; b0.z=bw[2]; b0.w=bw[3];              \
        b1.x=bw[4]; b1.y=bw[5]; b1.z=bw[6]; b1.w=bw[7];              \
        *(uint4*)&B_lds[arow * 40 + aq * 16]     = b0;               \
        *(uint4*)&B_lds[arow * 40 + aq * 16 + 8] = b1;               \
    } while (0)

    const int wave = tid >> 6, lane = tid & 63;
    const int wr = (wave & 1) * 64;    // row group
    const int wc = (wave >> 1) * 64;   // col group
    const int fr = lane & 15;
    const int koff = (lane >> 4) * 8;

    floatx4 acc[4][4];
#pragma unroll
    for (int i = 0; i < 4; i++)
#pragma unroll
        for (int j = 0; j < 4; j++) acc[i][j] = (floatx4){0.f, 0.f, 0.f, 0.f};

    LOAD_REGS(0);
    WRITE_LDS();

    for (int kk = 0; kk < 8; ++kk) {
        if (kk < 7) LOAD_REGS(kk + 1);
        __syncthreads();
        short8 af[4], bf[4];
#pragma unroll
        for (int t = 0; t < 4; t++) {
            af[t] = *(const short8*)&A_lds[(wr + t * 16 + fr) * 40 + koff];
            bf[t] = *(const short8*)&B_lds[(wc + t * 16 + fr) * 40 + koff];
        }
#pragma unroll
        for (int rt = 0; rt < 4; rt++)
#pragma unroll
            for (int ct = 0; ct < 4; ct++)
                acc[rt][ct] = __builtin_amdgcn_mfma_f32_16x16x32_bf16(
                    bf[ct], af[rt], acc[rt][ct], 0, 0, 0);
        __syncthreads();
        if (kk < 7) WRITE_LDS();
    }

    // epilogue: D col(lane&15)=emb row, D row((lane>>4)*4+reg)=h col
#pragma unroll
    for (int rt = 0; rt < 4; rt++) {
        int lrow = wr + rt * 16 + fr;
        int grow = m0 + lrow;
        float sc = sscale[lrow];
        if (grow < n) {
#pragma unroll
            for (int ct = 0; ct < 4; ct++) {
                int col = wc + ct * 16 + (lane >> 4) * 4;
                union { unsigned short s[4]; uint2 v; } o;
                o.s[0] = f2bf(acc[rt][ct][0] * sc);
                o.s[1] = f2bf(acc[rt][ct][1] * sc);
                o.s[2] = f2bf(acc[rt][ct][2] * sc);
                o.s[3] = f2bf(acc[rt][ct][3] * sc);
                *(uint2*)&h[(size_t)grow * OUT_DIM + col] = o.v;
            }
        }
    }
#undef LOAD_REGS
#undef WRITE_LDS
}

// ---------------------------------------------------------------------------
// Kernel 6: CSR-SpMM + norm + bias. One wave per row; coalesced index load +
// shfl broadcast; 16 outstanding h-row gathers; non-temporal feat stores.
// ---------------------------------------------------------------------------
__global__ __launch_bounds__(256) void spmm_csr_kernel(
    const int* __restrict__ row_start, const int* __restrict__ csr_src,
    const unsigned short* __restrict__ h, const float* __restrict__ bias,
    float* __restrict__ out_feat, int n)
{
    const int lane = threadIdx.x & 63;
    const int c2 = lane * 2;
    const int row = blockIdx.x * 4 + (threadIdx.x >> 6);
    if (row >= n) return;

    const int rs = row_start[row];
    const int re = row_start[row + 1];
    const int deg = re - rs;

    float aL[4] = {0.f, 0.f, 0.f, 0.f};
    float aH[4] = {0.f, 0.f, 0.f, 0.f};

    for (int base = 0; base < deg; base += 64) {
        const int cnt = min(deg - base, 64);
        int idx = (lane < cnt) ? csr_src[rs + base + lane] : 0;
        int t = 0;
        for (; t + 15 < cnt; t += 16) {
            int s[16];
#pragma unroll
            for (int u = 0; u < 16; u++) s[u] = __shfl(idx, t + u, 64);
            unsigned v[16];
#pragma unroll
            for (int u = 0; u < 16; u++)
                v[u] = *(const unsigned*)&h[(size_t)s[u] * OUT_DIM + c2];
#pragma unroll
            for (int u = 0; u < 16; u++) {
                union { unsigned uu; float f; } x, y;
                x.uu = v[u] << 16;
                y.uu = v[u] & 0xffff0000u;
                aL[u & 3] += x.f;
                aH[u & 3] += y.f;
            }
        }
        for (; t + 3 < cnt; t += 4) {
            int s[4];
#pragma unroll
            for (int u = 0; u < 4; u++) s[u] = __shfl(idx, t + u, 64);
            unsigned v[4];
#pragma unroll
            for (int u = 0; u < 4; u++)
                v[u] = *(const unsigned*)&h[(size_t)s[u] * OUT_DIM + c2];
#pragma unroll
            for (int u = 0; u < 4; u++) {
                union { unsigned uu; float f; } x, y;
                x.uu = v[u] << 16;
                y.uu = v[u] & 0xffff0000u;
                aL[u] += x.f;
                aH[u] += y.f;
            }
        }
        for (; t < cnt; ++t) {
            int s0 = __shfl(idx, t, 64);
            unsigned v0 = *(const unsigned*)&h[(size_t)s0 * OUT_DIM + c2];
            union { unsigned uu; float f; } x, y;
            x.uu = v0 << 16;
            y.uu = v0 & 0xffff0000u;
            aL[0] += x.f;
            aH[0] += y.f;
        }
    }

    const float nd = rsqrtf(fmaxf((float)deg, 1.0f));
    const float f0 = ((aL[0] + aL[1]) + (aL[2] + aL[3])) * nd + bias[c2];
    const float f1 = ((aH[0] + aH[1]) + (aH[2] + aH[3])) * nd + bias[c2 + 1];
    union { float f[2]; unsigned long long u; } o;
    o.f[0] = f0; o.f[1] = f1;
    __builtin_nontemporal_store(o.u,
        (unsigned long long*)&out_feat[(size_t)row * OUT_DIM + c2]);
}

// ---------------------------------------------------------------------------
// Kernel 7: logits = F @ mlp_w + mlp_b via MFMA; non-temporal stores.
// ---------------------------------------------------------------------------
__global__ __launch_bounds__(256) void mlp_mfma_kernel(
    const float* __restrict__ F, const float* __restrict__ mlp_w,
    const float* __restrict__ mlp_b, float* __restrict__ out_logits, int n)
{
    __shared__ unsigned short A_lds[48 * 136];
    __shared__ float s_mlpb[48];

    const int tid = threadIdx.x;
    for (int i = tid; i < 48 * 128; i += 256) {
        int cls = i >> 7, k = i & 127;
        A_lds[cls * 136 + k] =
            (cls < N_CLS) ? f2bf(mlp_w[(size_t)k * N_CLS + cls]) : (unsigned short)0;
    }
    if (tid < 48) s_mlpb[tid] = (tid < N_CLS) ? mlp_b[tid] : 0.f;
    __syncthreads();

    const int wave = tid >> 6, lane = tid & 63;
    const int r = lane & 15, koff = (lane >> 4) * 8;
    const int row = blockIdx.x * 64 + wave * 16 + r;
    const int rowc = (row < n) ? row : (n - 1);
    const float* fp = F + (size_t)rowc * OUT_DIM + koff;

    floatx4 acc[3];
#pragma unroll
    for (int ct = 0; ct < 3; ct++) acc[ct] = (floatx4){0.f, 0.f, 0.f, 0.f};

#pragma unroll
    for (int kk = 0; kk < 4; kk++) {
        floatx4 v0 = *(const floatx4*)(fp + kk * 32);
        floatx4 v1 = *(const floatx4*)(fp + kk * 32 + 4);
        union { unsigned short s[8]; short8 v; } bfr;
#pragma unroll
        for (int i = 0; i < 4; i++) {
            bfr.s[i]     = f2bf(v0[i]);
            bfr.s[4 + i] = f2bf(v1[i]);
        }
#pragma unroll
        for (int ct = 0; ct < 3; ct++) {
            short8 af = *(const short8*)&A_lds[(ct * 16 + r) * 136 + kk * 32 + koff];
            acc[ct] = __builtin_amdgcn_mfma_f32_16x16x32_bf16(af, bfr.v, acc[ct], 0, 0, 0);
        }
    }

    if (row < n) {
#pragma unroll
        for (int ct = 0; ct < 3; ct++)
#pragma unroll
            for (int i = 0; i < 4; i++) {
                int cls = ct * 16 + (lane >> 4) * 4 + i;
                if (cls < N_CLS)
                    __builtin_nontemporal_store(acc[ct][i] + s_mlpb[cls],
                        &out_logits[(size_t)row * N_CLS + cls]);
            }
    }
}

// ---------------------------------------------------------------------------
extern "C" void kernel_launch(void* const* d_in, const int* in_sizes, int n_in,
                              void* d_out, int out_size, void* d_ws, size_t ws_size,
                              hipStream_t stream) {
    const int*   nodes = (const int*)d_in[0];
    const int*   src   = (const int*)d_in[1];
    const int*   dst   = (const int*)d_in[2];
    const float* emb   = (const float*)d_in[3];
    const float* W     = (const float*)d_in[4];
    const float* b     = (const float*)d_in[5];
    const float* mlp_w = (const float*)d_in[6];
    const float* mlp_b = (const float*)d_in[7];

    const int n  = in_sizes[0];   // 50000
    const int ne = in_sizes[1];   // 800000

    // ws layout (ints): cnt_out[n] | cnt_in[n] | row_start[n+8] | csr_src[ne]
    //   | partial_out[NE_CH*n] | partial_in[NE_CH*n] | bf16 Wt | bf16 h[n*128]
    int* cnt_out     = (int*)d_ws;
    int* cnt_in      = cnt_out + n;
    int* row_start   = cnt_in + n;
    int* csr_src     = row_start + n + 8;
    int* partial_out = csr_src + ne;
    int* partial_in  = partial_out + (size_t)NE_CH * n;
    size_t off = ((size_t)(3 * n + 8) + (size_t)ne + 2 * (size_t)NE_CH * n) * sizeof(int);
    off = (off + 15) & ~(size_t)15;
    unsigned short* Wt = (unsigned short*)((char*)d_ws + off);
    off += (size_t)IN_DIM * OUT_DIM * sizeof(unsigned short);
    off = (off + 15) & ~(size_t)15;
    unsigned short* h = (unsigned short*)((char*)d_ws + off);

    float* out_feat   = (float*)d_out;                    // n*128
    float* out_logits = out_feat + (size_t)n * OUT_DIM;   // n*40

    const int ns = (n + SLICE - 1) / SLICE;               // 7
    const int chunk = (((ne + NE_CH - 1) / NE_CH) + 3) & ~3;
    const int nbh = ns * NE_CH;                           // 140 hist blocks
    const int nbw = (IN_DIM * OUT_DIM + 255) / 256;       // 128 wconv blocks

    hist_wconv_kernel<<<nbh + nbw, 256, 0, stream>>>(
        src, dst, partial_out, partial_in, W, Wt, ne, n, chunk, nbh);
    reduce_kernel<<<((n >> 2) + 255) / 256, 256, 0, stream>>>(
        partial_out, partial_in, cnt_out, cnt_in, n);
    scan_kernel<<<1, 1024, 0, stream>>>(cnt_in, row_start, n);
    scatter_lds_kernel<<<nbh, 256, 0, stream>>>(
        src, dst, row_start, partial_in, csr_src, ne, n, chunk);
    gemm1_mfma_kernel<<<(n + 127) / 128, 256, 0, stream>>>(nodes, emb, Wt, cnt_out, h, n);
    spmm_csr_kernel<<<(n + 3) / 4, 256, 0, stream>>>(
        row_start, csr_src, h, b, out_feat, n);
    mlp_mfma_kernel<<<(n + 63) / 64, 256, 0, stream>>>(
        out_feat, mlp_w, mlp_b, out_logits, n);
}